// Round 1
// baseline (925.954 us; speedup 1.0000x reference)
//
#include <hip/hip_runtime.h>
#include <cfloat>
#include <climits>

#define BQ 128      // number of queries (B)
#define DD 64       // feature dim
#define KK 10       // top-k
#define CHUNK_MAX 2048
#define P2T 256     // phase-2 threads

__device__ __forceinline__ bool pair_less(float d1, int i1, float d2, int i2) {
    return (d1 < d2) || (d1 == d2 && i1 < i2);
}

// Maintain sorted-ascending (by (key, idx)) top-K in registers. d/ix must be
// accessed with compile-time indices only (fully unrolled) so they stay in VGPRs.
__device__ __forceinline__ void topk_insert(float (&d)[KK], int (&ix)[KK], float key, int idx) {
    if (!pair_less(key, idx, d[KK - 1], ix[KK - 1])) return;
    d[KK - 1] = key; ix[KK - 1] = idx;
#pragma unroll
    for (int j = KK - 1; j > 0; --j) {
        bool sw = pair_less(d[j], ix[j], d[j - 1], ix[j - 1]);
        float dt = d[j - 1]; int it = ix[j - 1];
        float du = d[j];     int iu = ix[j];
        d[j - 1] = sw ? du : dt; ix[j - 1] = sw ? iu : it;
        d[j]     = sw ? dt : du; ix[j]     = sw ? it : iu;
    }
}

// Phase 1: each block handles a chunk of pool rows for ALL 128 queries.
// lane = query; pool-row reads are wave-uniform (hope: s_load scalar path).
__global__ __launch_bounds__(BQ) void phase1_topk(
        const float* __restrict__ x, const float* __restrict__ pool_x,
        float* __restrict__ cand_d, int* __restrict__ cand_i,
        int N, int C, int chunk) {
    __shared__ float psq[CHUNK_MAX];
    const int t  = threadIdx.x;
    const int bx = blockIdx.x;
    const int r0 = bx * chunk;
    const int r1 = min(N, r0 + chunk);
    const int nr = r1 - r0;

    // Stage A: per-row squared norms into LDS (cooperative, coalesced-ish).
    for (int rr = t; rr < nr; rr += BQ) {
        const float4* p4 = reinterpret_cast<const float4*>(pool_x) + (size_t)(r0 + rr) * (DD / 4);
        float s0 = 0.f, s1 = 0.f, s2 = 0.f, s3 = 0.f;
#pragma unroll
        for (int j = 0; j < DD / 4; ++j) {
            float4 p = p4[j];
            s0 += p.x * p.x; s1 += p.y * p.y; s2 += p.z * p.z; s3 += p.w * p.w;
        }
        psq[rr] = (s0 + s1) + (s2 + s3);
    }

    // Stage B: this thread's query row into registers (64 VGPRs).
    float4 xv[DD / 4];
    const float4* x4 = reinterpret_cast<const float4*>(x) + (size_t)t * (DD / 4);
#pragma unroll
    for (int j = 0; j < DD / 4; ++j) xv[j] = x4[j];

    __syncthreads();

    float d[KK]; int ix[KK];
#pragma unroll
    for (int j = 0; j < KK; ++j) { d[j] = FLT_MAX; ix[j] = INT_MAX; }

    // Main loop: wave-uniform pool-row loads, 64 fmacs per row per thread.
    for (int rr = 0; rr < nr; ++rr) {
        const float4* p4 = reinterpret_cast<const float4*>(pool_x) + (size_t)(r0 + rr) * (DD / 4);
        float a0 = 0.f, a1 = 0.f, a2 = 0.f, a3 = 0.f;
#pragma unroll
        for (int j = 0; j < DD / 4; ++j) {
            float4 p = __ldg(p4 + j);
            a0 += p.x * xv[j].x;
            a1 += p.y * xv[j].y;
            a2 += p.z * xv[j].z;
            a3 += p.w * xv[j].w;
        }
        float key = psq[rr] - 2.0f * ((a0 + a1) + (a2 + a3));
        topk_insert(d, ix, key, r0 + rr);
    }

    // Emit this block's per-query top-10 candidates. Layout [q][C*10] so
    // phase 2 reads are coalesced.
    size_t base = ((size_t)t * C + bx) * KK;
#pragma unroll
    for (int j = 0; j < KK; ++j) { cand_d[base + j] = d[j]; cand_i[base + j] = ix[j]; }
}

// Phase 2: one block per query. Merge C*10 candidates -> final top-10, gather output.
__global__ __launch_bounds__(P2T) void phase2_merge_gather(
        const float* __restrict__ cand_d, const int* __restrict__ cand_i,
        const float* __restrict__ pool_x, const float* __restrict__ pool_y,
        float* __restrict__ out, int C) {
    __shared__ float ld[2][P2T * KK];
    __shared__ int   li[2][P2T * KK];
    const int t = threadIdx.x;
    const int q = blockIdx.x;
    const int M = C * KK;

    float d[KK]; int ix[KK];
#pragma unroll
    for (int j = 0; j < KK; ++j) { d[j] = FLT_MAX; ix[j] = INT_MAX; }

    const float* cd = cand_d + (size_t)q * M;
    const int*   ci = cand_i + (size_t)q * M;
    for (int c = t; c < M; c += P2T) topk_insert(d, ix, cd[c], ci[c]);

#pragma unroll
    for (int j = 0; j < KK; ++j) { ld[0][t * KK + j] = d[j]; li[0][t * KK + j] = ix[j]; }
    __syncthreads();

    int buf = 0;
    for (int w = P2T / 4; w >= 1; w /= 4) {   // 64, 16, 4, 1
        if (t < w) {
            float e[KK]; int ei[KK];
#pragma unroll
            for (int j = 0; j < KK; ++j) { e[j] = FLT_MAX; ei[j] = INT_MAX; }
            int src = t * 4 * KK;
            for (int c = 0; c < 4 * KK; ++c)
                topk_insert(e, ei, ld[buf][src + c], li[buf][src + c]);
#pragma unroll
            for (int j = 0; j < KK; ++j) { ld[1 - buf][t * KK + j] = e[j]; li[1 - buf][t * KK + j] = ei[j]; }
        }
        __syncthreads();
        buf ^= 1;
    }
    // Final sorted-ascending top-10 now in ld/li[buf][0..KK). (buf == 0 here.)

    // Cooperative gather: out[q][j][c] = c<64 ? pool_x[idx][c] : pool_y[idx]
    for (int e = t; e < KK * (DD + 1); e += P2T) {
        int j = e / (DD + 1);
        int c = e - j * (DD + 1);
        int idx = li[buf][j];
        float v = (c < DD) ? pool_x[(size_t)idx * DD + c] : pool_y[idx];
        out[((size_t)q * KK + j) * (DD + 1) + c] = v;
    }
}

extern "C" void kernel_launch(void* const* d_in, const int* in_sizes, int n_in,
                              void* d_out, int out_size, void* d_ws, size_t ws_size,
                              hipStream_t stream) {
    const float* x      = (const float*)d_in[0];
    const float* pool_x = (const float*)d_in[1];
    const float* pool_y = (const float*)d_in[2];
    // d_in[3] = size_retrieval_set (==10), compile-time KK.

    const int N = in_sizes[1] / DD;

    // Pick chunk so candidate buffers fit in workspace.
    int chunk = 256;
    while (chunk < CHUNK_MAX) {
        int Ctry = (N + chunk - 1) / chunk;
        if ((size_t)BQ * Ctry * KK * 8 <= ws_size) break;
        chunk *= 2;
    }
    const int C = (N + chunk - 1) / chunk;

    float* cand_d = (float*)d_ws;
    int*   cand_i = (int*)(cand_d + (size_t)BQ * C * KK);

    hipLaunchKernelGGL(phase1_topk, dim3(C), dim3(BQ), 0, stream,
                       x, pool_x, cand_d, cand_i, N, C, chunk);
    hipLaunchKernelGGL(phase2_merge_gather, dim3(BQ), dim3(P2T), 0, stream,
                       cand_d, cand_i, pool_x, pool_y, (float*)d_out, C);
}

// Round 2
// 287.924 us; speedup vs baseline: 3.2160x; 3.2160x over previous
//
#include <hip/hip_runtime.h>
#include <cfloat>
#include <climits>

typedef short  short8v __attribute__((ext_vector_type(8)));
typedef float  f32x4   __attribute__((ext_vector_type(4)));

#define TILE_R 64   // pool rows staged per block-iteration
#define NQ     128  // number of queries (fixed by problem)
#define K1     4    // per-lane top-k in phase 1
#define K2     6    // per-lane top-k in phase 2 stream scan
#define KSEL   24   // approx top-K kept for exact rescore (margin over 10)
#define KK     10   // final k

__device__ __forceinline__ bool pair_less(float d1, int i1, float d2, int i2) {
    return (d1 < d2) || (d1 == d2 && i1 < i2);
}

__device__ __forceinline__ unsigned short bf16_rne(float f) {
    unsigned u = __float_as_uint(f);
    u += 0x7FFFu + ((u >> 16) & 1u);
    return (unsigned short)(u >> 16);
}

// Branchless-after-entry sorted insert, float-key only (phase-1 streams are
// index-ascending, so strict < gives correct stable tie-breaks).
__device__ __forceinline__ void ins4(float (&d)[K1], int (&ix)[K1], float key, int idx) {
    if (!(key < d[K1 - 1])) return;   // NaN-safe: NaN never inserts
    d[K1 - 1] = key; ix[K1 - 1] = idx;
#pragma unroll
    for (int j = K1 - 1; j > 0; --j) {
        float a = d[j - 1], b = d[j]; int ai = ix[j - 1], bi = ix[j];
        bool sw = b < a;
        d[j - 1] = sw ? b : a; ix[j - 1] = sw ? bi : ai;
        d[j]     = sw ? a : b; ix[j]     = sw ? ai : bi;
    }
}

__device__ __forceinline__ void ins6(float (&d)[K2], int (&ix)[K2], float key, int idx) {
    if (!pair_less(key, idx, d[K2 - 1], ix[K2 - 1])) return;
    d[K2 - 1] = key; ix[K2 - 1] = idx;
#pragma unroll
    for (int j = K2 - 1; j > 0; --j) {
        float a = d[j - 1], b = d[j]; int ai = ix[j - 1], bi = ix[j];
        bool sw = pair_less(b, bi, a, ai);
        d[j - 1] = sw ? b : a; ix[j - 1] = sw ? bi : ai;
        d[j]     = sw ? a : b; ix[j]     = sw ? ai : bi;
    }
}

// 64-lane argmin of (key, idx) with lane tie-break; all lanes get the result.
__device__ __forceinline__ void argmin64(float& k, int& i, int& l) {
#pragma unroll
    for (int off = 32; off; off >>= 1) {
        float ok = __shfl_xor(k, off);
        int   oi = __shfl_xor(i, off);
        int   ol = __shfl_xor(l, off);
        bool take = pair_less(ok, oi, k, i) || (ok == k && oi == i && ol < l);
        k = take ? ok : k; i = take ? oi : i; l = take ? ol : l;
    }
}

// ---------------- Phase 1: bf16-MFMA scoring + per-lane top-4 filter --------
// Block = 256 threads (4 waves). Wave w handles queries [32w, 32w+32) as two
// 16-query MFMA tile-columns. Pool rows staged 64/iter into LDS in
// MFMA-A-fragment-linear order (lane-linear ds_read_b128, conflict-free).
__global__ __launch_bounds__(256) void phase1(
        const float* __restrict__ x, const float* __restrict__ pool_x,
        float* __restrict__ cand_d, int* __restrict__ cand_i,
        int N, int rows_per_block) {
    __shared__ short lds_a[TILE_R * 64];   // bf16 bits, fragment-linear
    __shared__ float lds_psq[TILE_R];

    const int t = threadIdx.x;
    const int wave = t >> 6, lane = t & 63;
    const int c = lane & 15, g = lane >> 4;
    const int r0 = blockIdx.x * rows_per_block;
    const int rend = min(N, r0 + rows_per_block);

    // B fragments: B[k][n] lane layout n=lane&15, k=(lane>>4)*8+j.
    short8v bfrag[2][2];
#pragma unroll
    for (int tt = 0; tt < 2; ++tt) {
        const float* xp = x + (32 * wave + 16 * tt + c) * 64;
#pragma unroll
        for (int ks = 0; ks < 2; ++ks) {
            const float4* p4 = (const float4*)(xp + ks * 32 + g * 8);
            float4 u0 = p4[0], u1 = p4[1];
            short8v s;
            s[0] = bf16_rne(u0.x); s[1] = bf16_rne(u0.y); s[2] = bf16_rne(u0.z); s[3] = bf16_rne(u0.w);
            s[4] = bf16_rne(u1.x); s[5] = bf16_rne(u1.y); s[6] = bf16_rne(u1.z); s[7] = bf16_rne(u1.w);
            bfrag[tt][ks] = s;
        }
    }

    float bd[2][K1]; int bi[2][K1];
#pragma unroll
    for (int tt = 0; tt < 2; ++tt)
#pragma unroll
        for (int j = 0; j < K1; ++j) { bd[tt][j] = FLT_MAX; bi[tt][j] = INT_MAX; }

    for (int rb = r0; rb < rend; rb += TILE_R) {
        // ---- stage 64 rows: thread (wave=srow, lane) loads row srow*16+c,
        // k-strips g and g+4 (8 fp32 each), converts to bf16, writes
        // fragment-linear so compute-side ds_read_b128 is lane-linear.
        {
            const int srow = wave;
            int row = rb + srow * 16 + c;
            bool ok = row < N;
            const float* pr = pool_x + (size_t)row * 64;
            float4 z = {0.f, 0.f, 0.f, 0.f};
            float4 a0 = ok ? ((const float4*)pr)[2 * g]     : z;
            float4 a1 = ok ? ((const float4*)pr)[2 * g + 1] : z;
            float4 a2 = ok ? ((const float4*)pr)[8 + 2 * g]     : z;
            float4 a3 = ok ? ((const float4*)pr)[8 + 2 * g + 1] : z;
            float s = a0.x * a0.x + a0.y * a0.y + a0.z * a0.z + a0.w * a0.w
                    + a1.x * a1.x + a1.y * a1.y + a1.z * a1.z + a1.w * a1.w
                    + a2.x * a2.x + a2.y * a2.y + a2.z * a2.z + a2.w * a2.w
                    + a3.x * a3.x + a3.y * a3.y + a3.z * a3.z + a3.w * a3.w;
            s += __shfl_xor(s, 16);
            s += __shfl_xor(s, 32);
            if (g == 0) lds_psq[srow * 16 + c] = ok ? s : FLT_MAX;
            short8v s0, s1;
            s0[0] = bf16_rne(a0.x); s0[1] = bf16_rne(a0.y); s0[2] = bf16_rne(a0.z); s0[3] = bf16_rne(a0.w);
            s0[4] = bf16_rne(a1.x); s0[5] = bf16_rne(a1.y); s0[6] = bf16_rne(a1.z); s0[7] = bf16_rne(a1.w);
            s1[0] = bf16_rne(a2.x); s1[1] = bf16_rne(a2.y); s1[2] = bf16_rne(a2.z); s1[3] = bf16_rne(a2.w);
            s1[4] = bf16_rne(a3.x); s1[5] = bf16_rne(a3.y); s1[6] = bf16_rne(a3.z); s1[7] = bf16_rne(a3.w);
            *(short8v*)&lds_a[((srow * 8 + g) * 16 + c) * 8]     = s0;
            *(short8v*)&lds_a[((srow * 8 + g + 4) * 16 + c) * 8] = s1;
        }
        __syncthreads();

        // ---- compute: 4 row-subtiles × 2 query-tiles × (K=64 as 2 MFMA)
#pragma unroll
        for (int sr = 0; sr < 4; ++sr) {
            short8v af0 = *(const short8v*)&lds_a[(sr * 128 + lane) * 8];
            short8v af1 = *(const short8v*)&lds_a[(sr * 128 + 64 + lane) * 8];
            f32x4 ps = *(const f32x4*)&lds_psq[sr * 16 + (g << 2)];
            int rowb = rb + sr * 16 + (g << 2);
#pragma unroll
            for (int tt = 0; tt < 2; ++tt) {
                f32x4 acc = {0.f, 0.f, 0.f, 0.f};
                acc = __builtin_amdgcn_mfma_f32_16x16x32_bf16(af0, bfrag[tt][0], acc, 0, 0, 0);
                acc = __builtin_amdgcn_mfma_f32_16x16x32_bf16(af1, bfrag[tt][1], acc, 0, 0, 0);
#pragma unroll
                for (int r = 0; r < 4; ++r) {
                    float key = ps[r] - 2.0f * acc[r];   // D-layout: row=g*4+r, col=c
                    ins4(bd[tt], bi[tt], key, rowb + r);
                }
            }
        }
        __syncthreads();
    }

    // ---- emit: cand[block][q][g*4+j]
#pragma unroll
    for (int tt = 0; tt < 2; ++tt) {
        int q = 32 * wave + 16 * tt + c;
        size_t base = ((size_t)blockIdx.x * NQ + q) * 16 + g * 4;
#pragma unroll
        for (int j = 0; j < K1; ++j) { cand_d[base + j] = bd[tt][j]; cand_i[base + j] = bi[tt][j]; }
    }
}

// ---------------- Phase 2: merge -> approx top-24 -> exact rescore -> top-10
__global__ __launch_bounds__(256) void phase2(
        const float* __restrict__ cand_d, const int* __restrict__ cand_i,
        const float* __restrict__ x, const float* __restrict__ pool_x,
        const float* __restrict__ pool_y, float* __restrict__ out,
        int nblocks, int N) {
    __shared__ float xs[64];
    __shared__ float wd[4 * KSEL]; __shared__ int wi[4 * KSEL];
    __shared__ float sd[KSEL];     __shared__ int si[KSEL];
    __shared__ float rk[64];
    __shared__ int   fi[KK];

    const int t = threadIdx.x, wave = t >> 6, lane = t & 63;
    const int q = blockIdx.x;
    if (t < 64) xs[t] = x[q * 64 + t];

    const int M = nblocks * 16;
    float d[K2]; int ix[K2];
#pragma unroll
    for (int j = 0; j < K2; ++j) { d[j] = FLT_MAX; ix[j] = INT_MAX; }

    for (int m = t; m < M; m += 256) {
        size_t o = ((size_t)(m >> 4) * NQ + q) * 16 + (m & 15);
        ins6(d, ix, cand_d[o], cand_i[o]);
    }

    // per-wave extraction of its top-KSEL (sorted lists -> iterative argmin+pop)
    for (int r = 0; r < KSEL; ++r) {
        float mk = d[0]; int mi = ix[0]; int ml = lane;
        argmin64(mk, mi, ml);
        if (lane == ml) {
#pragma unroll
            for (int j = 0; j < K2 - 1; ++j) { d[j] = d[j + 1]; ix[j] = ix[j + 1]; }
            d[K2 - 1] = FLT_MAX; ix[K2 - 1] = INT_MAX;
        }
        if (lane == 0) { wd[wave * KSEL + r] = mk; wi[wave * KSEL + r] = mi; }
    }
    __syncthreads();

    // wave 0 merges 4×KSEL=96 -> global approx top-KSEL
    if (wave == 0) {
        float e0 = wd[lane]; int e0i = wi[lane];
        float e1 = (lane + 64 < 4 * KSEL) ? wd[lane + 64] : FLT_MAX;
        int  e1i = (lane + 64 < 4 * KSEL) ? wi[lane + 64] : INT_MAX;
        if (pair_less(e1, e1i, e0, e0i)) {
            float tf = e0; e0 = e1; e1 = tf;
            int   ti = e0i; e0i = e1i; e1i = ti;
        }
        for (int r = 0; r < KSEL; ++r) {
            float mk = e0; int mi = e0i; int ml = lane;
            argmin64(mk, mi, ml);
            if (lane == ml) { e0 = e1; e0i = e1i; e1 = FLT_MAX; e1i = INT_MAX; }
            if (lane == 0) { sd[r] = mk; si[r] = mi; }
        }
    }
    __syncthreads();

    // exact fp32 rescore of the KSEL survivors
    if (t < 64) {
        float key = FLT_MAX;
        if (t < KSEL) {
            int idx = si[t];
            if (idx >= 0 && idx < N) {
                const float4* pr = (const float4*)(pool_x + (size_t)idx * 64);
                const float4* xv = (const float4*)xs;
                float psq = 0.f, dot = 0.f;
#pragma unroll
                for (int k4 = 0; k4 < 16; ++k4) {
                    float4 p = pr[k4]; float4 xw = xv[k4];
                    psq += p.x * p.x + p.y * p.y + p.z * p.z + p.w * p.w;
                    dot += p.x * xw.x + p.y * xw.y + p.z * xw.z + p.w * xw.w;
                }
                key = psq - 2.0f * dot;
            }
        }
        rk[t] = key;
    }
    __syncthreads();

    // exact top-10 (key, idx) — matches reference stable ascending-sort semantics
    if (wave == 0) {
        float mykey = rk[lane];
        int myidx = (lane < KSEL) ? si[lane] : INT_MAX;
        for (int r = 0; r < KK; ++r) {
            float mk = mykey; int mi = myidx; int ml = lane;
            argmin64(mk, mi, ml);
            if (lane == ml) { mykey = FLT_MAX; myidx = INT_MAX; }
            if (lane == 0) fi[r] = mi;
        }
    }
    __syncthreads();

    // gather output rows: [q][j][0:64]=pool_x[idx], [q][j][64]=pool_y[idx]
    for (int e = t; e < KK * 65; e += 256) {
        int j = e / 65, cdim = e - j * 65;
        int idx = fi[j];
        out[(size_t)q * (KK * 65) + e] = (cdim < 64) ? pool_x[(size_t)idx * 64 + cdim]
                                                     : pool_y[idx];
    }
}

extern "C" void kernel_launch(void* const* d_in, const int* in_sizes, int n_in,
                              void* d_out, int out_size, void* d_ws, size_t ws_size,
                              hipStream_t stream) {
    const float* x      = (const float*)d_in[0];
    const float* pool_x = (const float*)d_in[1];
    const float* pool_y = (const float*)d_in[2];
    const int N = in_sizes[1] / 64;

    int rows_per_block = 512;   // multiple of TILE_R
    while (true) {
        int nb = (N + rows_per_block - 1) / rows_per_block;
        size_t need = (size_t)nb * NQ * 16 * (sizeof(float) + sizeof(int));
        if (need <= ws_size || rows_per_block >= (1 << 20)) break;
        rows_per_block *= 2;
    }
    const int nblocks = (N + rows_per_block - 1) / rows_per_block;

    float* cand_d = (float*)d_ws;
    int*   cand_i = (int*)(cand_d + (size_t)nblocks * NQ * 16);

    hipLaunchKernelGGL(phase1, dim3(nblocks), dim3(256), 0, stream,
                       x, pool_x, cand_d, cand_i, N, rows_per_block);
    hipLaunchKernelGGL(phase2, dim3(NQ), dim3(256), 0, stream,
                       cand_d, cand_i, x, pool_x, pool_y, (float*)d_out, nblocks, N);
}